// Round 1
// baseline (2834.443 us; speedup 1.0000x reference)
//
#include <hip/hip_runtime.h>
#include <math.h>

#define BB 32
#define TT 1024
#define INF 256
#define HH 128
#define G4 512   // 4*H

// =============== GEMM: C[m,n] = sum_k A[m,k]*W[n,k] + (bih[n]+bhh[n]) ===============
// A: 32768 x 256 row-major. W (per dir): 512 x 256 row-major. C: per-dir 32768 x 512.
// BM=64 BN=64 BK=16, 256 threads, 4x4 micro-tile per thread.
__global__ __launch_bounds__(256) void gemm_inproj(
    const float* __restrict__ A,        // 32768 x 256
    const float* __restrict__ w_ih_l,   // 2 x 512 x 256  (this layer's slice)
    const float* __restrict__ b_ih_l,   // 2 x 512
    const float* __restrict__ b_hh_l,   // 2 x 512
    float* __restrict__ xproj)          // 2 x 32768 x 512
{
    const int d  = blockIdx.z;
    const float* W = w_ih_l + (size_t)d * G4 * INF;
    float* C = xproj + (size_t)d * 32768 * 512;
    const int m0 = blockIdx.y * 64;
    const int n0 = blockIdx.x * 64;
    const int tid = threadIdx.x;
    const int tx = tid & 15, ty = tid >> 4;

    __shared__ __align__(16) float As[16 * 68];
    __shared__ __align__(16) float Bs[16 * 68];

    float acc[4][4] = {};
    const int lr = tid >> 2;        // 0..63 : row within tile for staging
    const int lk = (tid & 3) * 4;   // k offset for staging

    for (int k0 = 0; k0 < 256; k0 += 16) {
        float4 a4 = *(const float4*)(A + (size_t)(m0 + lr) * 256 + k0 + lk);
        float4 b4 = *(const float4*)(W + (size_t)(n0 + lr) * 256 + k0 + lk);
        __syncthreads();   // previous micro-loop done before overwriting LDS
        As[(lk + 0) * 68 + lr] = a4.x; As[(lk + 1) * 68 + lr] = a4.y;
        As[(lk + 2) * 68 + lr] = a4.z; As[(lk + 3) * 68 + lr] = a4.w;
        Bs[(lk + 0) * 68 + lr] = b4.x; Bs[(lk + 1) * 68 + lr] = b4.y;
        Bs[(lk + 2) * 68 + lr] = b4.z; Bs[(lk + 3) * 68 + lr] = b4.w;
        __syncthreads();
#pragma unroll
        for (int kk = 0; kk < 16; ++kk) {
            float4 av = *(const float4*)&As[kk * 68 + ty * 4];
            float4 bv = *(const float4*)&Bs[kk * 68 + tx * 4];
            float ar[4] = {av.x, av.y, av.z, av.w};
            float br[4] = {bv.x, bv.y, bv.z, bv.w};
#pragma unroll
            for (int i = 0; i < 4; ++i)
#pragma unroll
                for (int j = 0; j < 4; ++j)
                    acc[i][j] += ar[i] * br[j];
        }
    }

    float bias[4];
#pragma unroll
    for (int j = 0; j < 4; ++j) {
        const int n = n0 + tx * 4 + j;
        bias[j] = b_ih_l[d * G4 + n] + b_hh_l[d * G4 + n];
    }
#pragma unroll
    for (int i = 0; i < 4; ++i) {
        float4 o;
        o.x = acc[i][0] + bias[0];
        o.y = acc[i][1] + bias[1];
        o.z = acc[i][2] + bias[2];
        o.w = acc[i][3] + bias[3];
        *(float4*)(C + (size_t)(m0 + ty * 4 + i) * 512 + n0 + tx * 4) = o;
    }
}

// =============== LSTM recurrence: one WG per (batch, direction) chain ===============
// xproj already contains x@Wih.T + b_ih + b_hh. Thread n owns gate row n (Whh in VGPRs).
__global__ __launch_bounds__(512) void lstm_rec(
    const float* __restrict__ xproj,   // 2 x B x T x 512
    const float* __restrict__ w_hh_l,  // 2 x 512 x 128 (this layer's slice)
    float* __restrict__ out)           // B x T x 256  ([fwd|bwd] concat)
{
    const int b = blockIdx.x & 31;
    const int d = blockIdx.x >> 5;
    const int n = threadIdx.x;

    __shared__ __align__(16) float h_lds[HH];
    __shared__ float g_lds[G4];

    float4 w[32];
    const float* wr = w_hh_l + (size_t)(d * G4 + n) * HH;
#pragma unroll
    for (int k = 0; k < 32; ++k) w[k] = *(const float4*)(wr + k * 4);

    if (n < HH) h_lds[n] = 0.f;
    float c = 0.f;
    __syncthreads();

    const float* xp = xproj + ((size_t)d * BB + b) * TT * 512;
    const int t0 = d ? (TT - 1) : 0;
    const int dt = d ? -1 : 1;

    float xv  = xp[(size_t)t0 * 512 + n];
    float xv1 = xp[(size_t)(t0 + dt) * 512 + n];

    float* ob = out + (size_t)b * TT * 256 + d * HH;

    for (int step = 0; step < TT; ++step) {
        const int t = t0 + dt * step;
        float xv2 = 0.f;
        if (step + 2 < TT) xv2 = xp[(size_t)(t + 2 * dt) * 512 + n];

        float acc = xv;
#pragma unroll
        for (int k = 0; k < 32; ++k) {
            float4 h4 = *(const float4*)&h_lds[k * 4];
            acc += w[k].x * h4.x + w[k].y * h4.y + w[k].z * h4.z + w[k].w * h4.w;
        }
        float act;
        if (n >= 256 && n < 384) act = tanhf(acc);           // g gate (wave-uniform branch)
        else                     act = 1.f / (1.f + expf(-acc)); // i, f, o gates
        g_lds[n] = act;
        __syncthreads();
        if (n < HH) {
            const float si = g_lds[n];
            const float sf = g_lds[HH + n];
            const float tg = g_lds[2 * HH + n];
            const float so = g_lds[3 * HH + n];
            c = sf * c + si * tg;
            const float h = so * tanhf(c);
            h_lds[n] = h;
            ob[(size_t)t * 256 + n] = h;
        }
        __syncthreads();
        xv = xv1; xv1 = xv2;
    }
}

// =============== Attention (last-row only) + FC ===============
// scores[b,t] = (r.out[b,t])/16 with r = wk.T @ q_last ; ctx = (softmax-avg of out) @ wv.T + bv
__global__ __launch_bounds__(256) void attn_kernel(
    const float* __restrict__ out1,  // B x T x 256
    const float* __restrict__ wq, const float* __restrict__ bq,
    const float* __restrict__ wk,
    const float* __restrict__ wv, const float* __restrict__ bv,
    const float* __restrict__ wfc, const float* __restrict__ bfc,
    float* __restrict__ outp)        // B x 4
{
    const int b = blockIdx.x;
    const int tid = threadIdx.x;
    __shared__ float xl[256], q[256], u[256], cx[256];
    __shared__ __align__(16) float r[256];
    __shared__ float sc[TT];
    __shared__ float red[256];

    const float* ob = out1 + (size_t)b * TT * 256;

    xl[tid] = ob[(size_t)(TT - 1) * 256 + tid];
    __syncthreads();

    // q_last = out[last] @ wq.T + bq
    float acc = bq[tid];
    const float* wqr = wq + (size_t)tid * 256;
#pragma unroll 4
    for (int k = 0; k < 256; ++k) acc += xl[k] * wqr[k];
    q[tid] = acc;
    __syncthreads();

    // r = q @ wk   (r[j] = sum_d q[d]*wk[d][j])
    acc = 0.f;
#pragma unroll 4
    for (int dd = 0; dd < 256; ++dd) acc += q[dd] * wk[(size_t)dd * 256 + tid];
    r[tid] = acc;
    __syncthreads();

    // scores: each wave handles t = wave, wave+4, ...
    const int wave = tid >> 6, lane = tid & 63;
    float4 r4 = *(const float4*)&r[lane * 4];
    for (int t = wave; t < TT; t += 4) {
        float4 o4 = *(const float4*)(ob + (size_t)t * 256 + lane * 4);
        float p = r4.x * o4.x + r4.y * o4.y + r4.z * o4.z + r4.w * o4.w;
#pragma unroll
        for (int off = 32; off > 0; off >>= 1) p += __shfl_down(p, off, 64);
        if (lane == 0) sc[t] = p * 0.0625f;   // 1/sqrt(256)
    }
    __syncthreads();

    // softmax over 1024
    float mx = -1e30f;
#pragma unroll
    for (int i = 0; i < 4; ++i) mx = fmaxf(mx, sc[tid + 256 * i]);
    red[tid] = mx; __syncthreads();
    for (int s = 128; s > 0; s >>= 1) {
        if (tid < s) red[tid] = fmaxf(red[tid], red[tid + s]);
        __syncthreads();
    }
    mx = red[0]; __syncthreads();
    float lsum = 0.f;
#pragma unroll
    for (int i = 0; i < 4; ++i) {
        float e = expf(sc[tid + 256 * i] - mx);
        sc[tid + 256 * i] = e;
        lsum += e;
    }
    __syncthreads();
    red[tid] = lsum; __syncthreads();
    for (int s = 128; s > 0; s >>= 1) {
        if (tid < s) red[tid] += red[tid + s];
        __syncthreads();
    }
    const float inv = 1.f / red[0];
    __syncthreads();

    // u = (sum_t p_t * out[t]) * inv
    acc = 0.f;
#pragma unroll 8
    for (int t = 0; t < TT; ++t) acc += sc[t] * ob[(size_t)t * 256 + tid];
    u[tid] = acc * inv;
    __syncthreads();

    // ctx = u @ wv.T + bv
    acc = bv[tid];
#pragma unroll 4
    for (int k = 0; k < 256; ++k) acc += u[k] * wv[(size_t)tid * 256 + k];
    cx[tid] = acc;
    __syncthreads();

    // out = ctx @ wfc.T + bfc
    if (tid < 4) {
        float o = bfc[tid];
        for (int k = 0; k < 256; ++k) o += cx[k] * wfc[tid * 256 + k];
        outp[b * 4 + tid] = o;
    }
}

extern "C" void kernel_launch(void* const* d_in, const int* in_sizes, int n_in,
                              void* d_out, int out_size, void* d_ws, size_t ws_size,
                              hipStream_t stream)
{
    const float* x    = (const float*)d_in[0];
    const float* w_ih = (const float*)d_in[1];
    const float* w_hh = (const float*)d_in[2];
    const float* b_ih = (const float*)d_in[3];
    const float* b_hh = (const float*)d_in[4];
    const float* wq   = (const float*)d_in[5];
    const float* wk   = (const float*)d_in[6];
    const float* wv   = (const float*)d_in[7];
    const float* bq   = (const float*)d_in[8];
    const float* bfcv = (const float*)d_in[12];
    const float* bv   = (const float*)d_in[10];
    const float* wfc  = (const float*)d_in[11];
    float* outp = (float*)d_out;

    float* ws    = (float*)d_ws;
    float* xproj = ws;                        // 2*32768*512 = 33,554,432 floats (128 MB)
    float* out0  = ws + 33554432;             // 8,388,608 floats (32 MB)
    float* out1  = out0 + 8388608;            // 8,388,608 floats (32 MB)

    dim3 gg(8, 512, 2);   // N-tiles, M-tiles, direction

    // layer 0
    gemm_inproj<<<gg, 256, 0, stream>>>(x, w_ih, b_ih, b_hh, xproj);
    lstm_rec<<<64, 512, 0, stream>>>(xproj, w_hh, out0);
    // layer 1
    gemm_inproj<<<gg, 256, 0, stream>>>(out0, w_ih + 2 * 512 * 256, b_ih + 1024, b_hh + 1024, xproj);
    lstm_rec<<<64, 512, 0, stream>>>(xproj, w_hh + 2 * 512 * 128, out1);
    // attention + fc
    attn_kernel<<<32, 256, 0, stream>>>(out1, wq, bq, wk, wv, bv, wfc, bfcv, outp);
}

// Round 2
// 2246.438 us; speedup vs baseline: 1.2617x; 1.2617x over previous
//
#include <hip/hip_runtime.h>
#include <math.h>

#define BB 32
#define TT 1024
#define INF 256
#define HH 128
#define G4 512   // 4*H

typedef _Float16 half2_t __attribute__((ext_vector_type(2)));

__device__ __forceinline__ float fdot2f(half2_t a, half2_t b, float c) {
#if defined(__has_builtin) && __has_builtin(__builtin_amdgcn_fdot2)
    return __builtin_amdgcn_fdot2(a, b, c, false);
#else
    return c + (float)a[0] * (float)b[0] + (float)a[1] * (float)b[1];
#endif
}

__device__ __forceinline__ float fast_sigmoid(float x) {
    return 1.0f / (1.0f + __expf(-x));
}
__device__ __forceinline__ float fast_tanh(float x) {
    return 1.0f - 2.0f / (__expf(2.0f * x) + 1.0f);
}

// =============== GEMM: C[m,n] = sum_k A[m,k]*W[n,k] + (bih[n]+bhh[n]) ===============
__global__ __launch_bounds__(256) void gemm_inproj(
    const float* __restrict__ A,        // 32768 x 256
    const float* __restrict__ w_ih_l,   // 2 x 512 x 256  (this layer's slice)
    const float* __restrict__ b_ih_l,   // 2 x 512
    const float* __restrict__ b_hh_l,   // 2 x 512
    float* __restrict__ xproj)          // 2 x 32768 x 512
{
    const int d  = blockIdx.z;
    const float* W = w_ih_l + (size_t)d * G4 * INF;
    float* C = xproj + (size_t)d * 32768 * 512;
    const int m0 = blockIdx.y * 64;
    const int n0 = blockIdx.x * 64;
    const int tid = threadIdx.x;
    const int tx = tid & 15, ty = tid >> 4;

    __shared__ __align__(16) float As[16 * 68];
    __shared__ __align__(16) float Bs[16 * 68];

    float acc[4][4] = {};
    const int lr = tid >> 2;        // 0..63 : row within tile for staging
    const int lk = (tid & 3) * 4;   // k offset for staging

    for (int k0 = 0; k0 < 256; k0 += 16) {
        float4 a4 = *(const float4*)(A + (size_t)(m0 + lr) * 256 + k0 + lk);
        float4 b4 = *(const float4*)(W + (size_t)(n0 + lr) * 256 + k0 + lk);
        __syncthreads();
        As[(lk + 0) * 68 + lr] = a4.x; As[(lk + 1) * 68 + lr] = a4.y;
        As[(lk + 2) * 68 + lr] = a4.z; As[(lk + 3) * 68 + lr] = a4.w;
        Bs[(lk + 0) * 68 + lr] = b4.x; Bs[(lk + 1) * 68 + lr] = b4.y;
        Bs[(lk + 2) * 68 + lr] = b4.z; Bs[(lk + 3) * 68 + lr] = b4.w;
        __syncthreads();
#pragma unroll
        for (int kk = 0; kk < 16; ++kk) {
            float4 av = *(const float4*)&As[kk * 68 + ty * 4];
            float4 bv = *(const float4*)&Bs[kk * 68 + tx * 4];
            float ar[4] = {av.x, av.y, av.z, av.w};
            float br[4] = {bv.x, bv.y, bv.z, bv.w};
#pragma unroll
            for (int i = 0; i < 4; ++i)
#pragma unroll
                for (int j = 0; j < 4; ++j)
                    acc[i][j] += ar[i] * br[j];
        }
    }

    float bias[4];
#pragma unroll
    for (int j = 0; j < 4; ++j) {
        const int n = n0 + tx * 4 + j;
        bias[j] = b_ih_l[d * G4 + n] + b_hh_l[d * G4 + n];
    }
#pragma unroll
    for (int i = 0; i < 4; ++i) {
        float4 o;
        o.x = acc[i][0] + bias[0];
        o.y = acc[i][1] + bias[1];
        o.z = acc[i][2] + bias[2];
        o.w = acc[i][3] + bias[3];
        *(float4*)(C + (size_t)(m0 + ty * 4 + i) * 512 + n0 + tx * 4) = o;
    }
}

// =============== LSTM recurrence: one WG of 256 per (batch, direction) chain ===============
// Thread j in [0,128): gates i_j (row j) and g_j (row 256+j); computes sig(i)*tanh(g).
// Thread 128+j: gates f_j (row 128+j) and o_j (row 384+j); owns (c_j, h_j) state.
// Weights + h in f16 (half2), dot via v_dot2_f32_f16, fp32 accumulate.
__global__ __launch_bounds__(256) void lstm_rec(
    const float* __restrict__ xproj,   // 2 x B x T x 512
    const float* __restrict__ w_hh_l,  // 2 x 512 x 128 (this layer's slice)
    float* __restrict__ out)           // B x T x 256  ([fwd|bwd] concat)
{
    const int b = blockIdx.x & 31;
    const int d = blockIdx.x >> 5;
    const int tid = threadIdx.x;
    const int jj = tid & 127;
    const bool lower = (tid < 128);

    const int row0 = lower ? jj : (128 + jj);        // i or f
    const int row1 = lower ? (256 + jj) : (384 + jj); // g or o

    __shared__ __align__(16) _Float16 hs[HH];   // h in f16
    __shared__ float p_ig[HH];                  // sig(i)*tanh(g)

    // ---- load + convert weights to half2 in VGPRs ----
    half2_t w0[64], w1[64];
    {
        const float* wr0 = w_hh_l + (size_t)(d * G4 + row0) * HH;
        const float* wr1 = w_hh_l + (size_t)(d * G4 + row1) * HH;
#pragma unroll
        for (int k = 0; k < 32; ++k) {
            float4 f0 = *(const float4*)(wr0 + 4 * k);
            float4 f1 = *(const float4*)(wr1 + 4 * k);
            w0[2 * k + 0] = half2_t{(_Float16)f0.x, (_Float16)f0.y};
            w0[2 * k + 1] = half2_t{(_Float16)f0.z, (_Float16)f0.w};
            w1[2 * k + 0] = half2_t{(_Float16)f1.x, (_Float16)f1.y};
            w1[2 * k + 1] = half2_t{(_Float16)f1.z, (_Float16)f1.w};
        }
    }

    if (lower) hs[jj] = (_Float16)0.f;
    float c = 0.f;
    __syncthreads();

    const float* xp = xproj + ((size_t)d * BB + b) * TT * 512;
    const int t0 = d ? (TT - 1) : 0;
    const int dt = d ? -1 : 1;

    float x0  = xp[(size_t)t0 * 512 + row0];
    float x1  = xp[(size_t)t0 * 512 + row1];
    float x0n = xp[(size_t)(t0 + dt) * 512 + row0];
    float x1n = xp[(size_t)(t0 + dt) * 512 + row1];

    float* ob = out + (size_t)b * TT * 256 + d * HH;

    for (int step = 0; step < TT; ++step) {
        const int t = t0 + dt * step;
        float x0p = 0.f, x1p = 0.f;
        if (step + 2 < TT) {
            x0p = xp[(size_t)(t + 2 * dt) * 512 + row0];
            x1p = xp[(size_t)(t + 2 * dt) * 512 + row1];
        }

        // ---- dot products: 2 gates x 128 over f16 h (broadcast LDS reads) ----
        float a00 = 0.f, a01 = 0.f, a10 = 0.f, a11 = 0.f;
        const float4* h4 = (const float4*)hs;
#pragma unroll
        for (int k = 0; k < 16; ++k) {
            float4 hv = h4[k];
            half2_t h0 = __builtin_bit_cast(half2_t, hv.x);
            half2_t h1 = __builtin_bit_cast(half2_t, hv.y);
            half2_t h2 = __builtin_bit_cast(half2_t, hv.z);
            half2_t h3 = __builtin_bit_cast(half2_t, hv.w);
            a00 = fdot2f(w0[4 * k + 0], h0, a00);
            a01 = fdot2f(w0[4 * k + 1], h1, a01);
            a00 = fdot2f(w0[4 * k + 2], h2, a00);
            a01 = fdot2f(w0[4 * k + 3], h3, a01);
            a10 = fdot2f(w1[4 * k + 0], h0, a10);
            a11 = fdot2f(w1[4 * k + 1], h1, a11);
            a10 = fdot2f(w1[4 * k + 2], h2, a10);
            a11 = fdot2f(w1[4 * k + 3], h3, a11);
        }
        const float p0 = x0 + a00 + a01;
        const float p1 = x1 + a10 + a11;

        float sf = 0.f, so = 0.f;
        if (lower) {
            const float si = fast_sigmoid(p0);
            const float tg = fast_tanh(p1);
            p_ig[jj] = si * tg;
        } else {
            sf = fast_sigmoid(p0);
            so = fast_sigmoid(p1);
        }
        __syncthreads();
        if (!lower) {
            c = sf * c + p_ig[jj];
            const float h = so * fast_tanh(c);
            ob[(size_t)t * 256 + jj] = h;
            hs[jj] = (_Float16)h;
        }
        __syncthreads();

        x0 = x0n; x1 = x1n;
        x0n = x0p; x1n = x1p;
    }
}

// =============== Attention (last-row only) + FC ===============
__global__ __launch_bounds__(256) void attn_kernel(
    const float* __restrict__ out1,  // B x T x 256
    const float* __restrict__ wq, const float* __restrict__ bq,
    const float* __restrict__ wk,
    const float* __restrict__ wv, const float* __restrict__ bv,
    const float* __restrict__ wfc, const float* __restrict__ bfc,
    float* __restrict__ outp)        // B x 4
{
    const int b = blockIdx.x;
    const int tid = threadIdx.x;
    __shared__ float xl[256], q[256], u[256], cx[256];
    __shared__ __align__(16) float r[256];
    __shared__ float sc[TT];
    __shared__ float red[256];

    const float* ob = out1 + (size_t)b * TT * 256;

    xl[tid] = ob[(size_t)(TT - 1) * 256 + tid];
    __syncthreads();

    float acc = bq[tid];
    const float* wqr = wq + (size_t)tid * 256;
#pragma unroll 4
    for (int k = 0; k < 256; ++k) acc += xl[k] * wqr[k];
    q[tid] = acc;
    __syncthreads();

    acc = 0.f;
#pragma unroll 4
    for (int dd = 0; dd < 256; ++dd) acc += q[dd] * wk[(size_t)dd * 256 + tid];
    r[tid] = acc;
    __syncthreads();

    const int wave = tid >> 6, lane = tid & 63;
    float4 r4 = *(const float4*)&r[lane * 4];
    for (int t = wave; t < TT; t += 4) {
        float4 o4 = *(const float4*)(ob + (size_t)t * 256 + lane * 4);
        float p = r4.x * o4.x + r4.y * o4.y + r4.z * o4.z + r4.w * o4.w;
#pragma unroll
        for (int off = 32; off > 0; off >>= 1) p += __shfl_down(p, off, 64);
        if (lane == 0) sc[t] = p * 0.0625f;
    }
    __syncthreads();

    float mx = -1e30f;
#pragma unroll
    for (int i = 0; i < 4; ++i) mx = fmaxf(mx, sc[tid + 256 * i]);
    red[tid] = mx; __syncthreads();
    for (int s = 128; s > 0; s >>= 1) {
        if (tid < s) red[tid] = fmaxf(red[tid], red[tid + s]);
        __syncthreads();
    }
    mx = red[0]; __syncthreads();
    float lsum = 0.f;
#pragma unroll
    for (int i = 0; i < 4; ++i) {
        float e = expf(sc[tid + 256 * i] - mx);
        sc[tid + 256 * i] = e;
        lsum += e;
    }
    __syncthreads();
    red[tid] = lsum; __syncthreads();
    for (int s = 128; s > 0; s >>= 1) {
        if (tid < s) red[tid] += red[tid + s];
        __syncthreads();
    }
    const float inv = 1.f / red[0];
    __syncthreads();

    acc = 0.f;
#pragma unroll 8
    for (int t = 0; t < TT; ++t) acc += sc[t] * ob[(size_t)t * 256 + tid];
    u[tid] = acc * inv;
    __syncthreads();

    acc = bv[tid];
#pragma unroll 4
    for (int k = 0; k < 256; ++k) acc += u[k] * wv[(size_t)tid * 256 + k];
    cx[tid] = acc;
    __syncthreads();

    if (tid < 4) {
        float o = bfc[tid];
        for (int k = 0; k < 256; ++k) o += cx[k] * wfc[tid * 256 + k];
        outp[b * 4 + tid] = o;
    }
}

extern "C" void kernel_launch(void* const* d_in, const int* in_sizes, int n_in,
                              void* d_out, int out_size, void* d_ws, size_t ws_size,
                              hipStream_t stream)
{
    const float* x    = (const float*)d_in[0];
    const float* w_ih = (const float*)d_in[1];
    const float* w_hh = (const float*)d_in[2];
    const float* b_ih = (const float*)d_in[3];
    const float* b_hh = (const float*)d_in[4];
    const float* wq   = (const float*)d_in[5];
    const float* wk   = (const float*)d_in[6];
    const float* wv   = (const float*)d_in[7];
    const float* bq   = (const float*)d_in[8];
    const float* bv   = (const float*)d_in[10];
    const float* wfc  = (const float*)d_in[11];
    const float* bfcv = (const float*)d_in[12];
    float* outp = (float*)d_out;

    float* ws    = (float*)d_ws;
    float* xproj = ws;                        // 2*32768*512 floats (128 MB)
    float* out0  = ws + 33554432;             // 8,388,608 floats (32 MB)
    float* out1  = out0 + 8388608;            // 8,388,608 floats (32 MB)

    dim3 gg(8, 512, 2);

    gemm_inproj<<<gg, 256, 0, stream>>>(x, w_ih, b_ih, b_hh, xproj);
    lstm_rec<<<64, 256, 0, stream>>>(xproj, w_hh, out0);
    gemm_inproj<<<gg, 256, 0, stream>>>(out0, w_ih + 2 * 512 * 256, b_ih + 1024, b_hh + 1024, xproj);
    lstm_rec<<<64, 256, 0, stream>>>(xproj, w_hh + 2 * 512 * 128, out1);
    attn_kernel<<<32, 256, 0, stream>>>(out1, wq, bq, wk, wv, bv, wfc, bfcv, outp);
}

// Round 3
// 2123.513 us; speedup vs baseline: 1.3348x; 1.0579x over previous
//
#include <hip/hip_runtime.h>
#include <math.h>

#define BB 32
#define TT 1024
#define INF 256
#define HH 128
#define G4 512   // 4*H
#define CH 16    // LSTM steps per LDS chunk

typedef _Float16 half2_t __attribute__((ext_vector_type(2)));

__device__ __forceinline__ float fdot2f(half2_t a, half2_t b, float c) {
    return __builtin_amdgcn_fdot2(a, b, c, false);
}
__device__ __forceinline__ float rcpf(float x) {
    return __builtin_amdgcn_rcpf(x);
}

// =============== GEMM: C[m,n] = sum_k A[m,k]*W[n,k] + (bih[n]+bhh[n]) ===============
// Prefetch next K-tile AFTER the staging barrier so the 16-k FMA block hides HBM latency
// (compiler emits vmcnt(0) before every s_barrier -> loads must not be freshly issued there).
__global__ __launch_bounds__(256) void gemm_inproj(
    const float* __restrict__ A,        // 32768 x 256
    const float* __restrict__ w_ih_l,   // 2 x 512 x 256  (this layer's slice)
    const float* __restrict__ b_ih_l,   // 2 x 512
    const float* __restrict__ b_hh_l,   // 2 x 512
    float* __restrict__ xproj)          // 2 x 32768 x 512
{
    const int d  = blockIdx.z;
    const float* W = w_ih_l + (size_t)d * G4 * INF;
    float* C = xproj + (size_t)d * 32768 * 512;
    const int m0 = blockIdx.y * 64;
    const int n0 = blockIdx.x * 64;
    const int tid = threadIdx.x;
    const int tx = tid & 15, ty = tid >> 4;

    __shared__ __align__(16) float As[16 * 68];
    __shared__ __align__(16) float Bs[16 * 68];

    float acc[4][4] = {};
    const int lr = tid >> 2;        // 0..63 : row within tile for staging
    const int lk = (tid & 3) * 4;   // k offset for staging

    float4 a_cur = *(const float4*)(A + (size_t)(m0 + lr) * 256 + lk);
    float4 b_cur = *(const float4*)(W + (size_t)(n0 + lr) * 256 + lk);

    for (int k0 = 0; k0 < 256; k0 += 16) {
        __syncthreads();   // previous micro-loop done before overwriting LDS
        As[(lk + 0) * 68 + lr] = a_cur.x; As[(lk + 1) * 68 + lr] = a_cur.y;
        As[(lk + 2) * 68 + lr] = a_cur.z; As[(lk + 3) * 68 + lr] = a_cur.w;
        Bs[(lk + 0) * 68 + lr] = b_cur.x; Bs[(lk + 1) * 68 + lr] = b_cur.y;
        Bs[(lk + 2) * 68 + lr] = b_cur.z; Bs[(lk + 3) * 68 + lr] = b_cur.w;
        __syncthreads();
        if (k0 + 16 < 256) {   // issue next tile loads; in flight during the FMA block
            a_cur = *(const float4*)(A + (size_t)(m0 + lr) * 256 + k0 + 16 + lk);
            b_cur = *(const float4*)(W + (size_t)(n0 + lr) * 256 + k0 + 16 + lk);
        }
#pragma unroll
        for (int kk = 0; kk < 16; ++kk) {
            float4 av = *(const float4*)&As[kk * 68 + ty * 4];
            float4 bv = *(const float4*)&Bs[kk * 68 + tx * 4];
            float ar[4] = {av.x, av.y, av.z, av.w};
            float br[4] = {bv.x, bv.y, bv.z, bv.w};
#pragma unroll
            for (int i = 0; i < 4; ++i)
#pragma unroll
                for (int j = 0; j < 4; ++j)
                    acc[i][j] += ar[i] * br[j];
        }
    }

    float bias[4];
#pragma unroll
    for (int j = 0; j < 4; ++j) {
        const int n = n0 + tx * 4 + j;
        bias[j] = b_ih_l[d * G4 + n] + b_hh_l[d * G4 + n];
    }
#pragma unroll
    for (int i = 0; i < 4; ++i) {
        float4 o;
        o.x = acc[i][0] + bias[0];
        o.y = acc[i][1] + bias[1];
        o.z = acc[i][2] + bias[2];
        o.w = acc[i][3] + bias[3];
        *(float4*)(C + (size_t)(m0 + ty * 4 + i) * 512 + n0 + tx * 4) = o;
    }
}

// =============== LSTM recurrence: one WG of 256 per (batch, direction) chain ===============
// Lanes 2j / 2j+1 handle h-element j:
//   even lane: gate rows j (i) and 256+j (g); passes sig(i)*tanh(g) via shfl_xor(1)
//   odd  lane: gate rows 128+j (f) and 384+j (o); owns (c_j, h_j)
// x staged per 16-step chunk in LDS (register-prefetched 1 chunk ahead);
// h output buffered in LDS, flushed per chunk. One barrier per step, no global
// ops in the step loop -> barrier drains are lgkmcnt-only.
__global__ __launch_bounds__(256, 1) void lstm_rec(
    const float* __restrict__ xproj,   // 2 x B x T x 512
    const float* __restrict__ w_hh_l,  // 2 x 512 x 128 (this layer's slice)
    float* __restrict__ out)           // B x T x 256  ([fwd|bwd] concat)
{
    const int b = blockIdx.x & 31;
    const int d = blockIdx.x >> 5;
    const int tid = threadIdx.x;
    const int odd = tid & 1;
    const int j = tid >> 1;                 // 0..127
    const int row0 = odd * 128 + j;         // i (even) or f (odd)
    const int row1 = row0 + 256;            // g (even) or o (odd)

    __shared__ __align__(16) _Float16 hs[HH];       // h in f16 (broadcast source)
    __shared__ __align__(16) float xbuf[CH * 512];  // 32 KB staged x-preactivations
    __shared__ __align__(16) float obuf[CH * HH];   // 8 KB h output buffer

    // ---- load + convert Whh rows to half2 in VGPRs ----
    half2_t w0[64], w1[64];
    {
        const float* wr0 = w_hh_l + (size_t)(d * G4 + row0) * HH;
        const float* wr1 = w_hh_l + (size_t)(d * G4 + row1) * HH;
#pragma unroll
        for (int k = 0; k < 32; ++k) {
            float4 f0 = *(const float4*)(wr0 + 4 * k);
            float4 f1 = *(const float4*)(wr1 + 4 * k);
            w0[2 * k + 0] = half2_t{(_Float16)f0.x, (_Float16)f0.y};
            w0[2 * k + 1] = half2_t{(_Float16)f0.z, (_Float16)f0.w};
            w1[2 * k + 0] = half2_t{(_Float16)f1.x, (_Float16)f1.y};
            w1[2 * k + 1] = half2_t{(_Float16)f1.z, (_Float16)f1.w};
        }
    }

    if (tid < HH) hs[tid] = (_Float16)0.f;
    float c = 0.f;

    const float* xp = xproj + ((size_t)d * BB + b) * TT * 512;
    float* ob = out + (size_t)b * TT * 256 + d * HH;

    // chunk ck covers global t range [tlo, tlo+15] staged in natural t order
    //   fwd: tlo = 16*ck,  step si -> lds_t = si
    //   bwd: tlo = 1008-16*ck, step si -> lds_t = 15-si
    float4 xr[8];
    {
        const float* g = xp + (size_t)(d ? 1008 : 0) * 512;
#pragma unroll
        for (int i = 0; i < 8; ++i) xr[i] = *(const float4*)(g + tid * 4 + i * 1024);
    }

    for (int ck = 0; ck < 64; ++ck) {
        // stage chunk ck (in regs) into LDS
#pragma unroll
        for (int i = 0; i < 8; ++i) *(float4*)&xbuf[tid * 4 + i * 1024] = xr[i];
        if (ck) {
            // flush obuf for chunk ck-1 (reads complete before the barrier below)
            const int idx = tid * 8;
            const int sf_ = idx >> 7;
            const int jf  = idx & 127;
            const int sg  = (ck - 1) * CH + sf_;
            const int t   = d ? (TT - 1 - sg) : sg;
            float4 o0 = *(const float4*)&obuf[idx];
            float4 o1 = *(const float4*)&obuf[idx + 4];
            *(float4*)&ob[(size_t)t * 256 + jf]     = o0;
            *(float4*)&ob[(size_t)t * 256 + jf + 4] = o1;
        }
        __syncthreads();
        // prefetch chunk ck+1 AFTER the barrier (so it is not drained here)
        if (ck + 1 < 64) {
            const int tlo = d ? (1008 - (ck + 1) * CH) : (ck + 1) * CH;
            const float* g = xp + (size_t)tlo * 512;
#pragma unroll
            for (int i = 0; i < 8; ++i) xr[i] = *(const float4*)(g + tid * 4 + i * 1024);
        }

        for (int si = 0; si < CH; ++si) {
            const int lds_t = d ? (CH - 1 - si) : si;
            const float px0 = xbuf[lds_t * 512 + row0];
            const float px1 = xbuf[lds_t * 512 + row1];

            float a00 = 0.f, a01 = 0.f, a10 = 0.f, a11 = 0.f;
            const float4* h4 = (const float4*)hs;
#pragma unroll
            for (int k = 0; k < 16; ++k) {
                float4 hv = h4[k];
                half2_t h0 = __builtin_bit_cast(half2_t, hv.x);
                half2_t h1 = __builtin_bit_cast(half2_t, hv.y);
                half2_t h2 = __builtin_bit_cast(half2_t, hv.z);
                half2_t h3 = __builtin_bit_cast(half2_t, hv.w);
                a00 = fdot2f(w0[4 * k + 0], h0, a00);
                a01 = fdot2f(w0[4 * k + 1], h1, a01);
                a00 = fdot2f(w0[4 * k + 2], h2, a00);
                a01 = fdot2f(w0[4 * k + 3], h3, a01);
                a10 = fdot2f(w1[4 * k + 0], h0, a10);
                a11 = fdot2f(w1[4 * k + 1], h1, a11);
                a10 = fdot2f(w1[4 * k + 2], h2, a10);
                a11 = fdot2f(w1[4 * k + 3], h3, a11);
            }
            const float p0 = px0 + a00 + a01;
            const float p1 = px1 + a10 + a11;

            // wave-uniform activations:
            //   v0 = sigmoid(p0)                        (i or f)
            //   even: v1 = tanh(p1) = 1 - 2/(e^{2p1}+1) ; odd: v1 = sigmoid(p1)
            const float v0 = rcpf(1.f + __expf(-p0));
            const float e1 = __expf(odd ? -p1 : 2.f * p1);
            const float r1 = rcpf(1.f + e1);
            const float v1 = odd ? r1 : 1.f - 2.f * r1;

            const float ig_in = __shfl_xor(v0 * v1, 1, 64);  // odd lane gets sig(i)*tanh(g)
            if (odd) {
                c = v0 * c + ig_in;
                const float th = 1.f - 2.f * rcpf(1.f + __expf(2.f * c));
                const float h = v1 * th;
                obuf[si * HH + j] = h;
                hs[j] = (_Float16)h;
            }
            __syncthreads();
        }
    }
    // final flush (chunk 63)
    {
        const int idx = tid * 8;
        const int sf_ = idx >> 7;
        const int jf  = idx & 127;
        const int sg  = 63 * CH + sf_;
        const int t   = d ? (TT - 1 - sg) : sg;
        float4 o0 = *(const float4*)&obuf[idx];
        float4 o1 = *(const float4*)&obuf[idx + 4];
        *(float4*)&ob[(size_t)t * 256 + jf]     = o0;
        *(float4*)&ob[(size_t)t * 256 + jf + 4] = o1;
    }
}

// =============== Attention (last-row only) + FC ===============
__global__ __launch_bounds__(256) void attn_kernel(
    const float* __restrict__ out1,  // B x T x 256
    const float* __restrict__ wq, const float* __restrict__ bq,
    const float* __restrict__ wk,
    const float* __restrict__ wv, const float* __restrict__ bv,
    const float* __restrict__ wfc, const float* __restrict__ bfc,
    float* __restrict__ outp)        // B x 4
{
    const int b = blockIdx.x;
    const int tid = threadIdx.x;
    __shared__ float xl[256], q[256], u[256], cx[256];
    __shared__ __align__(16) float r[256];
    __shared__ float sc[TT];
    __shared__ float red[256];

    const float* ob = out1 + (size_t)b * TT * 256;

    xl[tid] = ob[(size_t)(TT - 1) * 256 + tid];
    __syncthreads();

    float acc = bq[tid];
    const float* wqr = wq + (size_t)tid * 256;
#pragma unroll 4
    for (int k = 0; k < 256; ++k) acc += xl[k] * wqr[k];
    q[tid] = acc;
    __syncthreads();

    acc = 0.f;
#pragma unroll 4
    for (int dd = 0; dd < 256; ++dd) acc += q[dd] * wk[(size_t)dd * 256 + tid];
    r[tid] = acc;
    __syncthreads();

    const int wave = tid >> 6, lane = tid & 63;
    float4 r4 = *(const float4*)&r[lane * 4];
    for (int t = wave; t < TT; t += 4) {
        float4 o4 = *(const float4*)(ob + (size_t)t * 256 + lane * 4);
        float p = r4.x * o4.x + r4.y * o4.y + r4.z * o4.z + r4.w * o4.w;
#pragma unroll
        for (int off = 32; off > 0; off >>= 1) p += __shfl_down(p, off, 64);
        if (lane == 0) sc[t] = p * 0.0625f;
    }
    __syncthreads();

    float mx = -1e30f;
#pragma unroll
    for (int i = 0; i < 4; ++i) mx = fmaxf(mx, sc[tid + 256 * i]);
    red[tid] = mx; __syncthreads();
    for (int s = 128; s > 0; s >>= 1) {
        if (tid < s) red[tid] = fmaxf(red[tid], red[tid + s]);
        __syncthreads();
    }
    mx = red[0]; __syncthreads();
    float lsum = 0.f;
#pragma unroll
    for (int i = 0; i < 4; ++i) {
        float e = expf(sc[tid + 256 * i] - mx);
        sc[tid + 256 * i] = e;
        lsum += e;
    }
    __syncthreads();
    red[tid] = lsum; __syncthreads();
    for (int s = 128; s > 0; s >>= 1) {
        if (tid < s) red[tid] += red[tid + s];
        __syncthreads();
    }
    const float inv = 1.f / red[0];
    __syncthreads();

    acc = 0.f;
#pragma unroll 8
    for (int t = 0; t < TT; ++t) acc += sc[t] * ob[(size_t)t * 256 + tid];
    u[tid] = acc * inv;
    __syncthreads();

    acc = bv[tid];
#pragma unroll 4
    for (int k = 0; k < 256; ++k) acc += u[k] * wv[(size_t)tid * 256 + k];
    cx[tid] = acc;
    __syncthreads();

    if (tid < 4) {
        float o = bfc[tid];
        for (int k = 0; k < 256; ++k) o += cx[k] * wfc[tid * 256 + k];
        outp[b * 4 + tid] = o;
    }
}

extern "C" void kernel_launch(void* const* d_in, const int* in_sizes, int n_in,
                              void* d_out, int out_size, void* d_ws, size_t ws_size,
                              hipStream_t stream)
{
    const float* x    = (const float*)d_in[0];
    const float* w_ih = (const float*)d_in[1];
    const float* w_hh = (const float*)d_in[2];
    const float* b_ih = (const float*)d_in[3];
    const float* b_hh = (const float*)d_in[4];
    const float* wq   = (const float*)d_in[5];
    const float* wk   = (const float*)d_in[6];
    const float* wv   = (const float*)d_in[7];
    const float* bq   = (const float*)d_in[8];
    const float* bv   = (const float*)d_in[10];
    const float* wfc  = (const float*)d_in[11];
    const float* bfcv = (const float*)d_in[12];
    float* outp = (float*)d_out;

    float* ws    = (float*)d_ws;
    float* xproj = ws;                        // 2*32768*512 floats (128 MB)
    float* out0  = ws + 33554432;             // 8,388,608 floats (32 MB)
    float* out1  = out0 + 8388608;            // 8,388,608 floats (32 MB)

    dim3 gg(8, 512, 2);

    gemm_inproj<<<gg, 256, 0, stream>>>(x, w_ih, b_ih, b_hh, xproj);
    lstm_rec<<<64, 256, 0, stream>>>(xproj, w_hh, out0);
    gemm_inproj<<<gg, 256, 0, stream>>>(out0, w_ih + 2 * 512 * 256, b_ih + 1024, b_hh + 1024, xproj);
    lstm_rec<<<64, 256, 0, stream>>>(xproj, w_hh + 2 * 512 * 128, out1);
    attn_kernel<<<32, 256, 0, stream>>>(out1, wq, bq, wk, wv, bv, wfc, bfcv, outp);
}